// Round 2
// baseline (674.723 us; speedup 1.0000x reference)
//
#include <hip/hip_runtime.h>
#include <hip/hip_bf16.h>
#include <cstdint>

// Problem constants
constexpr int Bn = 128, Tn = 200, NCn = 3, NBn = 2, Dn = 512, DHn = 256;
constexpr int GROUPS = Bn * Tn * NCn;        // 76800 (b,t,c) groups
constexpr int TOKS   = GROUPS * NBn;         // 153600 tokens
// out rows per batch: 600 dist + 1200 tok = 1800

typedef __bf16 bf16x8 __attribute__((ext_vector_type(8)));
typedef float  f32x4  __attribute__((ext_vector_type(4)));

__device__ __forceinline__ unsigned short f2b(float f) {
    union { float f; unsigned int u; } x; x.f = f;
    unsigned int r = x.u + 0x7fffu + ((x.u >> 16) & 1u);   // RNE
    return (unsigned short)(r >> 16);
}

__device__ __forceinline__ f32x4 ld4(const float* __restrict__ p) {
    return *reinterpret_cast<const f32x4*>(p);
}

// ---------------- kernel T: w2 (256x512 f32) -> w2t (512x256 bf16) ----------------
__global__ __launch_bounds__(256) void k_tr(const float* __restrict__ w2,
                                            unsigned short* __restrict__ w2t) {
    int idx = blockIdx.x * 256 + threadIdx.x;      // 131072 total
    int n = idx >> 8, k = idx & 255;
    w2t[idx] = f2b(w2[k * Dn + n]);
}

// ---------------- kernel M: prep + MLP + MFMA GEMM (verified orientation) + epilogue + dist ----------------
// 64 tokens (32 groups) per block, 256 threads (4 waves), grid = 2400
__global__ __launch_bounds__(256) void k_main(
    const float* __restrict__ bd,
    const float* __restrict__ cat_table,
    const float* __restrict__ w1,
    const float* __restrict__ b1,
    const float* __restrict__ ln_g,
    const float* __restrict__ ln_b,
    const float* __restrict__ b2v,
    const float* __restrict__ conf_w,
    const float* __restrict__ conf_b,
    const float* __restrict__ center_w,
    const float* __restrict__ center_b,
    const float* __restrict__ missing,
    const float* __restrict__ cam_table,
    const float* __restrict__ scale_p,
    const float* __restrict__ dist_w,
    const float* __restrict__ dist_b,
    const unsigned short* __restrict__ w2t,
    float* __restrict__ out) {

    __shared__ float s_geom[64][12];
    __shared__ float s_scal[64][4];                 // conf, cx, cy, code(cat + 4*(1-pres))
    __shared__ unsigned short s_a[64 * 264];        // A tile, stride 264 bf16 (pad vs 256)

    const int tid = threadIdx.x;
    const int tb  = blockIdx.x * 64;                // first global token of this block

    // ---- prep: 32 groups by threads 0..31 ----
    if (tid < 32) {
        int g = blockIdx.x * 32 + tid;
        const float* p = bd + (size_t)g * 12;
        float v[12];
        #pragma unroll
        for (int i = 0; i < 12; i++) v[i] = p[i];
        float cn[2][4];
        cn[0][0] = v[0] / 640.f; cn[0][1] = v[1] / 400.f; cn[0][2] = v[2] / 640.f; cn[0][3] = v[3] / 400.f;
        cn[1][0] = v[6] / 640.f; cn[1][1] = v[7] / 400.f; cn[1][2] = v[8] / 640.f; cn[1][3] = v[9] / 400.f;
        float catv[2] = { v[4], v[10] };
        float cnfv[2] = { v[5], v[11] };
        float sum0 = cn[0][0] + cn[0][1] + cn[0][2] + cn[0][3];
        float sum1 = cn[1][0] + cn[1][1] + cn[1][2] + cn[1][3];
        float pr0 = (sum0 != 0.f) ? 1.f : 0.f;
        float pr1 = (sum1 != 0.f) ? 1.f : 0.f;
        float key0 = catv[0] + (1.f - pr0) * 1000.f;
        float key1 = catv[1] + (1.f - pr1) * 1000.f;
        int sw = (key1 < key0) ? 1 : 0;             // stable argsort over 2 elements
        #pragma unroll
        for (int s = 0; s < 2; s++) {
            int src = s ^ sw;
            float x1 = cn[src][0], y1 = cn[src][1], x2 = cn[src][2], y2 = cn[src][3];
            float wd = x2 - x1, ht = y2 - y1;
            float cx = (x1 + x2) * 0.5f, cy = (y1 + y2) * 0.5f;
            float area = wd * ht, asp = wd / (ht + 1e-6f);
            float pres = ((x1 + y1 + x2 + y2) != 0.f) ? 1.f : 0.f;
            int lt = tid * 2 + s;
            s_geom[lt][0] = x1; s_geom[lt][1] = y1; s_geom[lt][2] = x2; s_geom[lt][3] = y2;
            s_geom[lt][4] = wd; s_geom[lt][5] = ht; s_geom[lt][6] = cx; s_geom[lt][7] = cy;
            s_geom[lt][8] = area; s_geom[lt][9] = asp; s_geom[lt][10] = 0.f; s_geom[lt][11] = 0.f;
            s_scal[lt][0] = cnfv[src]; s_scal[lt][1] = cx; s_scal[lt][2] = cy;
            s_scal[lt][3] = catv[src] + ((pres == 0.f) ? 4.f : 0.f);
        }
    }
    __syncthreads();

    const int w = tid >> 6, lane = tid & 63;

    // ---- phase B: h = gelu(LN(geom @ w1 + b1)) -> s_a (bf16), per wave 16 tokens ----
    {
        const int c0 = lane * 4;                    // 4 consecutive DH columns per lane
        f32x4 w1r[10], b1r, gr, br;
        #pragma unroll
        for (int f = 0; f < 10; f++) w1r[f] = ld4(w1 + f * DHn + c0);
        b1r = ld4(b1 + c0); gr = ld4(ln_g + c0); br = ld4(ln_b + c0);
        for (int i = 0; i < 16; i++) {
            int lt = w * 16 + i;
            float gm[10];
            #pragma unroll
            for (int f = 0; f < 10; f++) gm[f] = s_geom[lt][f];
            float x[4];
            #pragma unroll
            for (int qq = 0; qq < 4; qq++) {
                float a = b1r[qq];
                #pragma unroll
                for (int f = 0; f < 10; f++) a += gm[f] * w1r[f][qq];
                x[qq] = a;
            }
            float s  = x[0] + x[1] + x[2] + x[3];
            float s2 = x[0]*x[0] + x[1]*x[1] + x[2]*x[2] + x[3]*x[3];
            #pragma unroll
            for (int m = 1; m < 64; m <<= 1) {
                s  += __shfl_xor(s,  m, 64);
                s2 += __shfl_xor(s2, m, 64);
            }
            float mu  = s * (1.f / 256.f);
            float var = s2 * (1.f / 256.f) - mu * mu;
            float rstd = rsqrtf(var + 1e-5f);
            ushort4 pk;
            #pragma unroll
            for (int qq = 0; qq < 4; qq++) {
                float t = (x[qq] - mu) * rstd * gr[qq] + br[qq];
                float y = 0.5f * t * (1.f + erff(t * 0.70710678118f));
                ((unsigned short*)&pk)[qq] = f2b(y);
            }
            *reinterpret_cast<ushort4*>(&s_a[lt * 264 + c0]) = pk;
        }
    }
    __syncthreads();

    // ---- phase C: GEMM (64x512, K=256) via mfma_f32_16x16x32_bf16 + epilogue ----
    // (verified orientation: mfma(h_frag, w2_frag) -> D row = token, col = n)
    const int mtp = w & 1;          // wave's M-tile pair: 0 -> tiles {0,1}, 1 -> {2,3}
    const int nh  = w >> 1;         // wave's N half: 0 -> nt 0..15, 1 -> 16..31
    const int r16 = lane & 15, q = lane >> 4;

    bf16x8 afr[2][8];
    #pragma unroll
    for (int mt = 0; mt < 2; mt++) {
        int row = (mtp * 2 + mt) * 16 + r16;
        const unsigned short* base = &s_a[row * 264 + q * 8];
        #pragma unroll
        for (int ks = 0; ks < 8; ks++)
            afr[mt][ks] = *reinterpret_cast<const bf16x8*>(base + ks * 32);
    }

    float rconf[8], rcx[8], rcy[8];
    int rcat[8], rcam[8];
    size_t rowoff[8];
    bool rpres[8];
    #pragma unroll
    for (int i = 0; i < 8; i++) {
        int mt = i >> 2, r = i & 3;
        int m = (mtp * 2 + mt) * 16 + q * 4 + r;
        rconf[i] = s_scal[m][0]; rcx[i] = s_scal[m][1]; rcy[i] = s_scal[m][2];
        int code = (int)s_scal[m][3];
        rcat[i] = code & 3; rpres[i] = (code < 4);
        int gt = tb + m;
        rcam[i] = (gt >> 1) % 3;
        int b = gt / 1200, rr = gt - b * 1200;
        rowoff[i] = ((size_t)b * 1800 + 600 + rr) * Dn;
    }
    float sc = scale_p[0];

    for (int ntl = 0; ntl < 16; ntl++) {
        int n = (nh * 16 + ntl) * 16 + r16;
        float cb  = b2v[n] + conf_b[n] + center_b[n];
        float cwv = conf_w[n];
        float c0v = center_w[n];
        float c1v = center_w[Dn + n];
        float msv = missing[n];

        f32x4 acc0 = {0.f, 0.f, 0.f, 0.f}, acc1 = {0.f, 0.f, 0.f, 0.f};
        const unsigned short* bbase = w2t + n * 256 + q * 8;
        #pragma unroll
        for (int ks = 0; ks < 8; ks++) {
            bf16x8 bf = *reinterpret_cast<const bf16x8*>(bbase + ks * 32);
            acc0 = __builtin_amdgcn_mfma_f32_16x16x32_bf16(afr[0][ks], bf, acc0, 0, 0, 0);
            acc1 = __builtin_amdgcn_mfma_f32_16x16x32_bf16(afr[1][ks], bf, acc1, 0, 0, 0);
        }
        #pragma unroll
        for (int i = 0; i < 8; i++) {
            int mt = i >> 2, r = i & 3;
            float a = (mt == 0) ? acc0[r] : acc1[r];
            float ce = cat_table[rcat[i] * Dn + n];
            float cm = cam_table[rcam[i] * Dn + n];
            float v = (a + cb + ce + rconf[i] * cwv + rcx[i] * c0v + rcy[i] * c1v + cm) * sc;
            if (!rpres[i]) v = msv;
            out[rowoff[i] + n] = v;
        }
    }

    // ---- phase D: dist rows for this block's 32 groups (replaces k_dist) ----
    // dist is invariant under the NB=2 sort; s_scal holds sorted cx,cy.
    {
        const int gl2 = tid >> 7;                   // 0 or 1
        const int col = (tid & 127) * 4;            // float4 column
        const f32x4 dwv = ld4(dist_w + col);
        const f32x4 dbv = ld4(dist_b + col);
        const int gblk = blockIdx.x * 32;
        for (int p = 0; p < 16; ++p) {
            int gl = p * 2 + gl2;
            float dx = s_scal[2 * gl][1] - s_scal[2 * gl + 1][1];
            float dy = s_scal[2 * gl][2] - s_scal[2 * gl + 1][2];
            float dist = sqrtf(dx * dx + dy * dy);
            int g = gblk + gl;
            int b = g / 600, r = g - b * 600;
            size_t ro = ((size_t)b * 1800 + r) * Dn + col;
            f32x4 v;
            #pragma unroll
            for (int r4 = 0; r4 < 4; r4++) v[r4] = dist * dwv[r4] + dbv[r4];
            *reinterpret_cast<f32x4*>(out + ro) = v;
        }
    }
}

extern "C" void kernel_launch(void* const* d_in, const int* in_sizes, int n_in,
                              void* d_out, int out_size, void* d_ws, size_t ws_size,
                              hipStream_t stream) {
    const float* bd        = (const float*)d_in[0];
    const float* cat_table = (const float*)d_in[1];
    const float* w1        = (const float*)d_in[2];
    const float* b1        = (const float*)d_in[3];
    const float* ln_g      = (const float*)d_in[4];
    const float* ln_b      = (const float*)d_in[5];
    const float* w2        = (const float*)d_in[6];
    const float* b2v       = (const float*)d_in[7];
    const float* conf_w    = (const float*)d_in[8];
    const float* conf_b    = (const float*)d_in[9];
    const float* center_w  = (const float*)d_in[10];
    const float* center_b  = (const float*)d_in[11];
    const float* missing   = (const float*)d_in[12];
    const float* dist_w    = (const float*)d_in[13];
    const float* dist_b    = (const float*)d_in[14];
    const float* cam_table = (const float*)d_in[15];
    const float* scale_p   = (const float*)d_in[16];
    float* out = (float*)d_out;
    unsigned short* w2t = (unsigned short*)d_ws;    // 512*256*2 = 262144 bytes

    hipLaunchKernelGGL(k_tr, dim3(512), dim3(256), 0, stream, w2, w2t);
    hipLaunchKernelGGL(k_main, dim3(TOKS / 64), dim3(256), 0, stream,
                       bd, cat_table, w1, b1, ln_g, ln_b, b2v, conf_w, conf_b,
                       center_w, center_b, missing, cam_table, scale_p,
                       dist_w, dist_b, w2t, out);
}